// Round 2
// baseline (134.503 us; speedup 1.0000x reference)
//
#include <hip/hip_runtime.h>
#include <math.h>

#define NCH    1024          // channels
#define NN     64            // nodes (8x8)
#define CK     32            // channels per staged chunk
#define KSC    28.853900817779268f   // 20 * log2(e)  (exp(-cost/0.05) = 2^((sim-1)*KSC))
#define SPLIT  4             // channel-split blocks per batch (kernel A)
#define WSB    4352          // floats per (batch,split) record: 4096 gram + 4*64 stats

// stats accumulation from staged registers
#define STAT_Q(v) { sqp[0]+=(v).x; q2p[0]=fmaf((v).x,(v).x,q2p[0]); \
                    sqp[1]+=(v).y; q2p[1]=fmaf((v).y,(v).y,q2p[1]); \
                    sqp[2]+=(v).z; q2p[2]=fmaf((v).z,(v).z,q2p[2]); \
                    sqp[3]+=(v).w; q2p[3]=fmaf((v).w,(v).w,q2p[3]); }
#define STAT_P(v) { spp[0]+=(v).x; p2p[0]=fmaf((v).x,(v).x,p2p[0]); \
                    spp[1]+=(v).y; p2p[1]=fmaf((v).y,(v).y,p2p[1]); \
                    spp[2]+=(v).z; p2p[2]=fmaf((v).z,(v).z,p2p[2]); \
                    spp[3]+=(v).w; p2p[3]=fmaf((v).w,(v).w,p2p[3]); }

#define GRAM_CHUNK_BODY(NCHUNK_, QB_, PB_)                                     \
    for (int ch = 0; ch < (NCHUNK_); ++ch) {                                   \
        if (ch) __syncthreads();                                               \
        *(float4*)&stage[       ofs] = qv0;                                    \
        *(float4*)&stage[1024 + ofs] = qv1;                                    \
        *(float4*)&stage[2048 + ofs] = pv0;                                    \
        *(float4*)&stage[3072 + ofs] = pv1;                                    \
        float4 nq0, nq1, np0, np1;                                             \
        const bool more = (ch + 1 < (NCHUNK_));                                \
        if (more) {                                                            \
            const float* qn = (QB_) + (ch + 1) * 2048;                         \
            const float* pn = (PB_) + (ch + 1) * 2048;                         \
            nq0 = *(const float4*)(qn + ofs);                                  \
            nq1 = *(const float4*)(qn + 1024 + ofs);                           \
            np0 = *(const float4*)(pn + ofs);                                  \
            np1 = *(const float4*)(pn + 1024 + ofs);                           \
        }                                                                      \
        STAT_Q(qv0); STAT_Q(qv1);                                              \
        STAT_P(pv0); STAT_P(pv1);                                              \
        __syncthreads();                                                       \
        _Pragma("unroll 8")                                                    \
        for (int cc = 0; cc < CK; ++cc) {                                      \
            float4 a  = *(const float4*)&stage[cc * 64 + n0];                  \
            float4 bb = *(const float4*)&stage[2048 + cc * 64 + m0];           \
            acc[0][0]=fmaf(a.x,bb.x,acc[0][0]); acc[0][1]=fmaf(a.x,bb.y,acc[0][1]); \
            acc[0][2]=fmaf(a.x,bb.z,acc[0][2]); acc[0][3]=fmaf(a.x,bb.w,acc[0][3]); \
            acc[1][0]=fmaf(a.y,bb.x,acc[1][0]); acc[1][1]=fmaf(a.y,bb.y,acc[1][1]); \
            acc[1][2]=fmaf(a.y,bb.z,acc[1][2]); acc[1][3]=fmaf(a.y,bb.w,acc[1][3]); \
            acc[2][0]=fmaf(a.z,bb.x,acc[2][0]); acc[2][1]=fmaf(a.z,bb.y,acc[2][1]); \
            acc[2][2]=fmaf(a.z,bb.z,acc[2][2]); acc[2][3]=fmaf(a.z,bb.w,acc[2][3]); \
            acc[3][0]=fmaf(a.w,bb.x,acc[3][0]); acc[3][1]=fmaf(a.w,bb.y,acc[3][1]); \
            acc[3][2]=fmaf(a.w,bb.z,acc[3][2]); acc[3][3]=fmaf(a.w,bb.w,acc[3][3]); \
        }                                                                      \
        if (more) { qv0 = nq0; qv1 = nq1; pv0 = np0; pv1 = np1; }              \
    }

#define DOT16(KK, ARR) ({ \
    float4 x0 = *(const float4*)&ARR[sp4*16 +  0]; \
    float4 x1 = *(const float4*)&ARR[sp4*16 +  4]; \
    float4 x2 = *(const float4*)&ARR[sp4*16 +  8]; \
    float4 x3 = *(const float4*)&ARR[sp4*16 + 12]; \
    float a0 = 0.0f, a1 = 0.0f; \
    a0=fmaf(KK[0],x0.x,a0);  a1=fmaf(KK[1],x0.y,a1); \
    a0=fmaf(KK[2],x0.z,a0);  a1=fmaf(KK[3],x0.w,a1); \
    a0=fmaf(KK[4],x1.x,a0);  a1=fmaf(KK[5],x1.y,a1); \
    a0=fmaf(KK[6],x1.z,a0);  a1=fmaf(KK[7],x1.w,a1); \
    a0=fmaf(KK[8],x2.x,a0);  a1=fmaf(KK[9],x2.y,a1); \
    a0=fmaf(KK[10],x2.z,a0); a1=fmaf(KK[11],x2.w,a1); \
    a0=fmaf(KK[12],x3.x,a0); a1=fmaf(KK[13],x3.y,a1); \
    a0=fmaf(KK[14],x3.z,a0); a1=fmaf(KK[15],x3.w,a1); \
    a0 + a1; })

// ===================== Kernel A: per-split Gram + stats partials =====================
// grid = 512*SPLIT blocks; block (b,s) handles channels [s*256, (s+1)*256).
__global__ __launch_bounds__(256)
void gram_partial(const float* __restrict__ proto,
                  const float* __restrict__ query,
                  float* __restrict__ ws)
{
    __shared__ __align__(16) float stage[4096];    // 16 KB: q-chunk | p-chunk; reused for stats dump

    const int bid = blockIdx.x;
    const int b = bid >> 2, s = bid & (SPLIT - 1);
    const int t  = threadIdx.x;
    const int tr = t >> 4, tc = t & 15;
    const int n0 = tr * 4, m0 = tc * 4;
    const int ofs = 4 * t;

    const float* __restrict__ pb = proto + (size_t)b * (NCH * NN) + s * (NCH / SPLIT) * NN;
    const float* __restrict__ qb = query + (size_t)b * (NCH * NN) + s * (NCH / SPLIT) * NN;

    float acc[4][4];
    #pragma unroll
    for (int i = 0; i < 4; ++i)
        #pragma unroll
        for (int j = 0; j < 4; ++j) acc[i][j] = 0.0f;
    float sqp[4] = {0,0,0,0}, q2p[4] = {0,0,0,0};
    float spp[4] = {0,0,0,0}, p2p[4] = {0,0,0,0};

    float4 qv0 = *(const float4*)(qb + ofs);
    float4 qv1 = *(const float4*)(qb + 1024 + ofs);
    float4 pv0 = *(const float4*)(pb + ofs);
    float4 pv1 = *(const float4*)(pb + 1024 + ofs);

    GRAM_CHUNK_BODY(NCH / SPLIT / CK, qb, pb)      // 8 chunks
    __syncthreads();

    // write gram partial [64][64]
    float* __restrict__ wsb = ws + (size_t)bid * WSB;
    #pragma unroll
    for (int i = 0; i < 4; ++i) {
        float4 v; v.x = acc[i][0]; v.y = acc[i][1]; v.z = acc[i][2]; v.w = acc[i][3];
        *(float4*)&wsb[(n0 + i) * 64 + m0] = v;
    }

    // stats partial reduce via stage, then write [4][64]
    #pragma unroll
    for (int k = 0; k < 4; ++k) {
        stage[t*16 +      k] = sqp[k];
        stage[t*16 +  4 + k] = q2p[k];
        stage[t*16 +  8 + k] = spp[k];
        stage[t*16 + 12 + k] = p2p[k];
    }
    __syncthreads();
    if (t < NN) {
        const int g = t >> 2, k = t & 3;
        float ssq = 0, sq2 = 0, ssp = 0, sp2 = 0;
        #pragma unroll
        for (int j = 0; j < 16; ++j) {
            const float* row = &stage[(j * 16 + g) * 16];
            ssq += row[k]; sq2 += row[4 + k]; ssp += row[8 + k]; sp2 += row[12 + k];
        }
        wsb[4096 +   0 + t] = ssq;
        wsb[4096 +  64 + t] = sq2;
        wsb[4096 + 128 + t] = ssp;
        wsb[4096 + 192 + t] = sp2;
    }
}

// ===================== Kernel B: combine + sim + K + Sinkhorn + logits =====================
__global__ __launch_bounds__(256)
void emd_solve(const float* __restrict__ ws, float* __restrict__ out)
{
    __shared__ __align__(16) float stage[16 * 64];          // colsum partials
    __shared__ __align__(16) float Kl [NN][68];
    __shared__ __align__(16) float KTl[NN][68];
    __shared__ __align__(16) float statL[4][NN];
    __shared__ __align__(16) float uL[NN];
    __shared__ __align__(16) float vL[NN];
    __shared__ __align__(16) float rL[NN];
    __shared__ __align__(16) float cL[NN];
    __shared__ float redl[4];

    const int b  = blockIdx.x;
    const int t  = threadIdx.x;
    const int tr = t >> 4, tc = t & 15;
    const int n0 = tr * 4, m0 = tc * 4;

    const float* __restrict__ wsb = ws + (size_t)b * SPLIT * WSB;

    // ---- combine gram partials ----
    float acc[4][4];
    #pragma unroll
    for (int i = 0; i < 4; ++i)
        #pragma unroll
        for (int j = 0; j < 4; ++j) acc[i][j] = 0.0f;
    #pragma unroll
    for (int s = 0; s < SPLIT; ++s) {
        const float* __restrict__ g = wsb + s * WSB;
        #pragma unroll
        for (int i = 0; i < 4; ++i) {
            float4 v = *(const float4*)&g[(n0 + i) * 64 + m0];
            acc[i][0] += v.x; acc[i][1] += v.y; acc[i][2] += v.z; acc[i][3] += v.w;
        }
    }
    // ---- combine stats ----
    if (t < NN) {
        float s0 = 0, s1 = 0, s2 = 0, s3 = 0;
        #pragma unroll
        for (int s = 0; s < SPLIT; ++s) {
            const float* __restrict__ g = wsb + s * WSB + 4096;
            s0 += g[t]; s1 += g[64 + t]; s2 += g[128 + t]; s3 += g[192 + t];
        }
        statL[0][t] = s0; statL[1][t] = s1; statL[2][t] = s2; statL[3][t] = s3;
    }
    // ---- row sums of raw Gram (-> weight_1) ----
    #pragma unroll
    for (int i = 0; i < 4; ++i) {
        float s = acc[i][0] + acc[i][1] + acc[i][2] + acc[i][3];
        s += __shfl_xor(s, 1, 64); s += __shfl_xor(s, 2, 64);
        s += __shfl_xor(s, 4, 64); s += __shfl_xor(s, 8, 64);
        if (tc == 0) uL[n0 + i] = s;
    }
    // ---- col-sum partials ----
    #pragma unroll
    for (int j = 0; j < 4; ++j)
        stage[tr * 64 + m0 + j] = acc[0][j] + acc[1][j] + acc[2][j] + acc[3][j];
    __syncthreads();

    // ---- weights / marginals (t<64) + sim/K (all threads), independent ----
    if (t < NN) {
        float cs = 0;
        #pragma unroll
        for (int i = 0; i < 16; ++i) cs += stage[i * 64 + t];
        float w2 = fmaxf(cs * (1.0f/64.0f), 0.0f) + 0.001f;
        float w1 = fmaxf(uL[t] * (1.0f/64.0f), 0.0f) + 0.001f;
        float s1 = w1, s2 = w2;
        #pragma unroll
        for (int m = 1; m < 64; m <<= 1) {
            s1 += __shfl_xor(s1, m, 64);
            s2 += __shfl_xor(s2, m, 64);
        }
        rL[t] = w1 / s1;
        cL[t] = w2 / s2;
        vL[t] = 1.0f;
    }
    {
        float nq_[4], np_[4], sqn[4], spm[4];
        #pragma unroll
        for (int i = 0; i < 4; ++i) {
            float sv  = statL[0][n0 + i];
            float var = statL[1][n0 + i] - sv * sv * (1.0f/1024.0f);
            nq_[i] = fmaxf(sqrtf(fmaxf(var, 0.0f)), 1e-8f);
            sqn[i] = sv;
        }
        #pragma unroll
        for (int j = 0; j < 4; ++j) {
            float sv  = statL[2][m0 + j];
            float var = statL[3][m0 + j] - sv * sv * (1.0f/1024.0f);
            np_[j] = fmaxf(sqrtf(fmaxf(var, 0.0f)), 1e-8f);
            spm[j] = sv;
        }
        #pragma unroll
        for (int i = 0; i < 4; ++i) {
            #pragma unroll
            for (int j = 0; j < 4; ++j) {
                float sim = (acc[i][j] - sqn[i] * spm[j] * (1.0f/1024.0f)) / (nq_[i] * np_[j]);
                acc[i][j] = sim;
                float Kv = exp2f((sim - 1.0f) * KSC);
                Kl [n0 + i][m0 + j] = Kv;
                KTl[m0 + j][n0 + i] = Kv;
            }
        }
    }
    __syncthreads();

    // ---- Sinkhorn: K row-slices in registers, 4 threads per row ----
    const int sn  = t >> 2;
    const int sp4 = t & 3;
    float Kr[16], KTr[16];
    #pragma unroll
    for (int jj = 0; jj < 4; ++jj) {
        float4 kv = *(const float4*)&Kl [sn][sp4 * 16 + jj * 4];
        float4 kt = *(const float4*)&KTl[sn][sp4 * 16 + jj * 4];
        Kr [jj*4+0]=kv.x; Kr [jj*4+1]=kv.y; Kr [jj*4+2]=kv.z; Kr [jj*4+3]=kv.w;
        KTr[jj*4+0]=kt.x; KTr[jj*4+1]=kt.y; KTr[jj*4+2]=kt.z; KTr[jj*4+3]=kt.w;
    }
    const float rreg = rL[sn];
    const float creg = cL[sn];

    for (int it = 0; it < 100; ++it) {
        float s = DOT16(Kr, vL);
        s += __shfl_xor(s, 1, 64); s += __shfl_xor(s, 2, 64);
        float u = rreg / fmaxf(s, 1e-30f);
        if (sp4 == 0) uL[sn] = u;
        __syncthreads();
        float s2 = DOT16(KTr, uL);
        s2 += __shfl_xor(s2, 1, 64); s2 += __shfl_xor(s2, 2, 64);
        float vv = creg / fmaxf(s2, 1e-30f);
        if (sp4 == 0) vL[sn] = vv;
        __syncthreads();
    }
    {
        float s = DOT16(Kr, vL);
        s += __shfl_xor(s, 1, 64); s += __shfl_xor(s, 2, 64);
        float u = rreg / fmaxf(s, 1e-30f);
        if (sp4 == 0) uL[sn] = u;
    }
    __syncthreads();

    // ---- logits = sum(sim * u*K*v) * (T / N) ----
    float uu[4], vv_[4];
    #pragma unroll
    for (int i = 0; i < 4; ++i) uu[i]  = uL[n0 + i];
    #pragma unroll
    for (int j = 0; j < 4; ++j) vv_[j] = vL[m0 + j];
    float part = 0.0f;
    #pragma unroll
    for (int i = 0; i < 4; ++i) {
        #pragma unroll
        for (int j = 0; j < 4; ++j) {
            float sim = acc[i][j];
            float Kv  = exp2f((sim - 1.0f) * KSC);
            part = fmaf(sim * Kv, uu[i] * vv_[j], part);
        }
    }
    #pragma unroll
    for (int m = 1; m < 64; m <<= 1) part += __shfl_xor(part, m, 64);
    if ((t & 63) == 0) redl[t >> 6] = part;
    __syncthreads();
    if (t == 0) out[b] = (redl[0] + redl[1] + redl[2] + redl[3]) * (12.5f / 64.0f);
}

// ===================== Fallback: verified fused single-kernel path =====================
__global__ __launch_bounds__(256)
void deepemd_fused(const float* __restrict__ proto,
                   const float* __restrict__ query,
                   float* __restrict__ out)
{
    __shared__ __align__(16) float stage[2 * CK * NN];
    __shared__ __align__(16) float Kl [NN][68];
    __shared__ __align__(16) float KTl[NN][68];
    __shared__ __align__(16) float statL[4][NN];
    __shared__ __align__(16) float uL[NN];
    __shared__ __align__(16) float vL[NN];
    __shared__ __align__(16) float rL[NN];
    __shared__ __align__(16) float cL[NN];
    __shared__ float redl[4];

    const int b  = blockIdx.x;
    const int t  = threadIdx.x;
    const int tr = t >> 4, tc = t & 15;
    const int n0 = tr * 4, m0 = tc * 4;
    const int ofs = 4 * t;

    const float* __restrict__ pb = proto + (size_t)b * (NCH * NN);
    const float* __restrict__ qb = query + (size_t)b * (NCH * NN);

    float acc[4][4];
    #pragma unroll
    for (int i = 0; i < 4; ++i)
        #pragma unroll
        for (int j = 0; j < 4; ++j) acc[i][j] = 0.0f;
    float sqp[4] = {0,0,0,0}, q2p[4] = {0,0,0,0};
    float spp[4] = {0,0,0,0}, p2p[4] = {0,0,0,0};

    float4 qv0 = *(const float4*)(qb + ofs);
    float4 qv1 = *(const float4*)(qb + 1024 + ofs);
    float4 pv0 = *(const float4*)(pb + ofs);
    float4 pv1 = *(const float4*)(pb + 1024 + ofs);

    GRAM_CHUNK_BODY(NCH / CK, qb, pb)
    __syncthreads();

    #pragma unroll
    for (int i = 0; i < 4; ++i) {
        float s = acc[i][0] + acc[i][1] + acc[i][2] + acc[i][3];
        s += __shfl_xor(s, 1, 64); s += __shfl_xor(s, 2, 64);
        s += __shfl_xor(s, 4, 64); s += __shfl_xor(s, 8, 64);
        if (tc == 0) uL[n0 + i] = s;
    }
    #pragma unroll
    for (int k = 0; k < 4; ++k) {
        stage[t*16 +      k] = sqp[k];
        stage[t*16 +  4 + k] = q2p[k];
        stage[t*16 +  8 + k] = spp[k];
        stage[t*16 + 12 + k] = p2p[k];
    }
    __syncthreads();
    if (t < NN) {
        const int g = t >> 2, k = t & 3;
        float ssq = 0, sq2 = 0, ssp = 0, sp2 = 0;
        #pragma unroll
        for (int j = 0; j < 16; ++j) {
            const float* row = &stage[(j * 16 + g) * 16];
            ssq += row[k]; sq2 += row[4 + k]; ssp += row[8 + k]; sp2 += row[12 + k];
        }
        statL[0][t] = ssq; statL[1][t] = sq2; statL[2][t] = ssp; statL[3][t] = sp2;
    }
    __syncthreads();
    #pragma unroll
    for (int j = 0; j < 4; ++j)
        stage[tr * 64 + m0 + j] = acc[0][j] + acc[1][j] + acc[2][j] + acc[3][j];
    __syncthreads();
    if (t < NN) {
        float cs = 0;
        #pragma unroll
        for (int i = 0; i < 16; ++i) cs += stage[i * 64 + t];
        float w2 = fmaxf(cs * (1.0f/64.0f), 0.0f) + 0.001f;
        float w1 = fmaxf(uL[t] * (1.0f/64.0f), 0.0f) + 0.001f;
        float s1 = w1, s2 = w2;
        #pragma unroll
        for (int m = 1; m < 64; m <<= 1) {
            s1 += __shfl_xor(s1, m, 64);
            s2 += __shfl_xor(s2, m, 64);
        }
        rL[t] = w1 / s1;
        cL[t] = w2 / s2;
        vL[t] = 1.0f;
    }
    __syncthreads();

    {
        float nq_[4], np_[4], sqn[4], spm[4];
        #pragma unroll
        for (int i = 0; i < 4; ++i) {
            float sv  = statL[0][n0 + i];
            float var = statL[1][n0 + i] - sv * sv * (1.0f/1024.0f);
            nq_[i] = fmaxf(sqrtf(fmaxf(var, 0.0f)), 1e-8f);
            sqn[i] = sv;
        }
        #pragma unroll
        for (int j = 0; j < 4; ++j) {
            float sv  = statL[2][m0 + j];
            float var = statL[3][m0 + j] - sv * sv * (1.0f/1024.0f);
            np_[j] = fmaxf(sqrtf(fmaxf(var, 0.0f)), 1e-8f);
            spm[j] = sv;
        }
        #pragma unroll
        for (int i = 0; i < 4; ++i) {
            #pragma unroll
            for (int j = 0; j < 4; ++j) {
                float sim = (acc[i][j] - sqn[i] * spm[j] * (1.0f/1024.0f)) / (nq_[i] * np_[j]);
                acc[i][j] = sim;
                float Kv = exp2f((sim - 1.0f) * KSC);
                Kl [n0 + i][m0 + j] = Kv;
                KTl[m0 + j][n0 + i] = Kv;
            }
        }
    }
    __syncthreads();

    const int sn  = t >> 2;
    const int sp4 = t & 3;
    float Kr[16], KTr[16];
    #pragma unroll
    for (int jj = 0; jj < 4; ++jj) {
        float4 kv = *(const float4*)&Kl [sn][sp4 * 16 + jj * 4];
        float4 kt = *(const float4*)&KTl[sn][sp4 * 16 + jj * 4];
        Kr [jj*4+0]=kv.x; Kr [jj*4+1]=kv.y; Kr [jj*4+2]=kv.z; Kr [jj*4+3]=kv.w;
        KTr[jj*4+0]=kt.x; KTr[jj*4+1]=kt.y; KTr[jj*4+2]=kt.z; KTr[jj*4+3]=kt.w;
    }
    const float rreg = rL[sn];
    const float creg = cL[sn];

    for (int it = 0; it < 100; ++it) {
        float s = DOT16(Kr, vL);
        s += __shfl_xor(s, 1, 64); s += __shfl_xor(s, 2, 64);
        float u = rreg / fmaxf(s, 1e-30f);
        if (sp4 == 0) uL[sn] = u;
        __syncthreads();
        float s2 = DOT16(KTr, uL);
        s2 += __shfl_xor(s2, 1, 64); s2 += __shfl_xor(s2, 2, 64);
        float vv = creg / fmaxf(s2, 1e-30f);
        if (sp4 == 0) vL[sn] = vv;
        __syncthreads();
    }
    {
        float s = DOT16(Kr, vL);
        s += __shfl_xor(s, 1, 64); s += __shfl_xor(s, 2, 64);
        float u = rreg / fmaxf(s, 1e-30f);
        if (sp4 == 0) uL[sn] = u;
    }
    __syncthreads();

    float uu[4], vv_[4];
    #pragma unroll
    for (int i = 0; i < 4; ++i) uu[i]  = uL[n0 + i];
    #pragma unroll
    for (int j = 0; j < 4; ++j) vv_[j] = vL[m0 + j];
    float part = 0.0f;
    #pragma unroll
    for (int i = 0; i < 4; ++i) {
        #pragma unroll
        for (int j = 0; j < 4; ++j) {
            float sim = acc[i][j];
            float Kv  = exp2f((sim - 1.0f) * KSC);
            part = fmaf(sim * Kv, uu[i] * vv_[j], part);
        }
    }
    #pragma unroll
    for (int m = 1; m < 64; m <<= 1) part += __shfl_xor(part, m, 64);
    if ((t & 63) == 0) redl[t >> 6] = part;
    __syncthreads();
    if (t == 0) out[b] = (redl[0] + redl[1] + redl[2] + redl[3]) * (12.5f / 64.0f);
}

extern "C" void kernel_launch(void* const* d_in, const int* in_sizes, int n_in,
                              void* d_out, int out_size, void* d_ws, size_t ws_size,
                              hipStream_t stream) {
    const float* proto = (const float*)d_in[0];
    const float* query = (const float*)d_in[1];
    float* out = (float*)d_out;
    (void)in_sizes; (void)n_in; (void)out_size;

    const size_t need = (size_t)512 * SPLIT * WSB * sizeof(float);   // ~35.7 MB
    if (ws_size >= need) {
        gram_partial<<<dim3(512 * SPLIT), dim3(256), 0, stream>>>(proto, query, (float*)d_ws);
        emd_solve  <<<dim3(512),         dim3(256), 0, stream>>>((const float*)d_ws, out);
    } else {
        deepemd_fused<<<dim3(512), dim3(256), 0, stream>>>(proto, query, out);
    }
}

// Round 3
// 131.902 us; speedup vs baseline: 1.0197x; 1.0197x over previous
//
#include <hip/hip_runtime.h>
#include <math.h>

#define NCH    1024          // channels
#define NN     64            // nodes (8x8)
#define CK     32            // channels per staged chunk (fused fallback)
#define KSC    28.853900817779268f   // 20 * log2(e)  (exp(-cost/0.05) = 2^((sim-1)*KSC))
#define SPLIT  4             // records per batch in ws
#define WSB    4352          // floats per record: 4096 gram + 4*64 stats
#define CHUNK_CH 8           // channels per staged chunk (kernel A2)
#define NCHUNKS  16          // 128 ch per wave / 8

// stats accumulation from staged registers
#define STAT_Q(v) { sqp[0]+=(v).x; q2p[0]=fmaf((v).x,(v).x,q2p[0]); \
                    sqp[1]+=(v).y; q2p[1]=fmaf((v).y,(v).y,q2p[1]); \
                    sqp[2]+=(v).z; q2p[2]=fmaf((v).z,(v).z,q2p[2]); \
                    sqp[3]+=(v).w; q2p[3]=fmaf((v).w,(v).w,q2p[3]); }
#define STAT_P(v) { spp[0]+=(v).x; p2p[0]=fmaf((v).x,(v).x,p2p[0]); \
                    spp[1]+=(v).y; p2p[1]=fmaf((v).y,(v).y,p2p[1]); \
                    spp[2]+=(v).z; p2p[2]=fmaf((v).z,(v).z,p2p[2]); \
                    spp[3]+=(v).w; p2p[3]=fmaf((v).w,(v).w,p2p[3]); }

// ===================== Kernel A2: wave-independent Gram partials, 8x8 tiles =====================
// grid = 512*SPLIT blocks x 128 threads. Block (b,s); wave w owns channels
// [s*256 + w*128, +128). Each lane computes an 8x8 tile of the 64x64 Gram.
// No barriers in the main loop (wave-coherent LDS); 2 barriers to merge waves.
__global__ __launch_bounds__(128, 3)
void gram_partial2(const float* __restrict__ proto,
                   const float* __restrict__ query,
                   float* __restrict__ ws)
{
    // staging: wave w, buf k: q at [w*2048 + k*1024], p at [+512]. 16 KB.
    // After the loop the whole array is reused as the wave-0 dump [64][64].
    __shared__ __align__(16) float smem[4096];
    __shared__ __align__(16) float statd[4][NN];

    const int bid = blockIdx.x;
    const int b = bid >> 2, s = bid & 3;
    const int t = threadIdx.x;
    const int w = t >> 6;            // wave id 0/1
    const int l = t & 63;            // lane
    const int r0 = (l >> 3) * 8;     // q-node rows owned
    const int c0 = (l & 7) * 8;      // p-node cols owned
    const int o1 = 4 * l;            // float offset within a 512-float chunk
    const int o2 = 256 + 4 * l;

    const float* __restrict__ qw = query + (size_t)b * (NCH * NN) + (s * 256 + w * 128) * NN;
    const float* __restrict__ pw = proto + (size_t)b * (NCH * NN) + (s * 256 + w * 128) * NN;

    float* const stg = &smem[w * 2048];

    float acc[8][8];
    #pragma unroll
    for (int i = 0; i < 8; ++i)
        #pragma unroll
        for (int j = 0; j < 8; ++j) acc[i][j] = 0.0f;
    float sqp[4] = {0,0,0,0}, q2p[4] = {0,0,0,0};
    float spp[4] = {0,0,0,0}, p2p[4] = {0,0,0,0};

    // prologue: chunk 0 into registers
    float4 qv0 = *(const float4*)(qw + o1);
    float4 qv1 = *(const float4*)(qw + o2);
    float4 pv0 = *(const float4*)(pw + o1);
    float4 pv1 = *(const float4*)(pw + o2);

    for (int ch = 0; ch < NCHUNKS; ++ch) {
        float* const sq = stg + (ch & 1) * 1024;
        float* const sp = sq + 512;
        *(float4*)(sq + o1) = qv0;
        *(float4*)(sq + o2) = qv1;
        *(float4*)(sp + o1) = pv0;
        *(float4*)(sp + o2) = pv1;

        // stats on the registers we just staged (nodes 4*(l&15)..+3)
        STAT_Q(qv0); STAT_Q(qv1);
        STAT_P(pv0); STAT_P(pv1);

        // issue next chunk's loads early (hide HBM latency under FMA loop)
        if (ch + 1 < NCHUNKS) {
            const float* qn = qw + (ch + 1) * 512;
            const float* pn = pw + (ch + 1) * 512;
            qv0 = *(const float4*)(qn + o1);
            qv1 = *(const float4*)(qn + o2);
            pv0 = *(const float4*)(pn + o1);
            pv1 = *(const float4*)(pn + o2);
        }

        // 8x8 outer-product accumulation from LDS (wave-local ordering only)
        #pragma unroll
        for (int cc = 0; cc < CHUNK_CH; ++cc) {
            float4 a0 = *(const float4*)(sq + cc * 64 + r0);
            float4 a1 = *(const float4*)(sq + cc * 64 + r0 + 4);
            float4 b0 = *(const float4*)(sp + cc * 64 + c0);
            float4 b1 = *(const float4*)(sp + cc * 64 + c0 + 4);
            const float av[8] = {a0.x,a0.y,a0.z,a0.w,a1.x,a1.y,a1.z,a1.w};
            const float bv[8] = {b0.x,b0.y,b0.z,b0.w,b1.x,b1.y,b1.z,b1.w};
            #pragma unroll
            for (int i = 0; i < 8; ++i)
                #pragma unroll
                for (int j = 0; j < 8; ++j)
                    acc[i][j] = fmaf(av[i], bv[j], acc[i][j]);
        }
    }

    // reduce stats across the 4 lane-groups that share node range (l&15)
    #pragma unroll
    for (int k = 0; k < 4; ++k) {
        sqp[k] += __shfl_xor(sqp[k], 16, 64); sqp[k] += __shfl_xor(sqp[k], 32, 64);
        q2p[k] += __shfl_xor(q2p[k], 16, 64); q2p[k] += __shfl_xor(q2p[k], 32, 64);
        spp[k] += __shfl_xor(spp[k], 16, 64); spp[k] += __shfl_xor(spp[k], 32, 64);
        p2p[k] += __shfl_xor(p2p[k], 16, 64); p2p[k] += __shfl_xor(p2p[k], 32, 64);
    }

    __syncthreads();                  // both waves done with staging buffers

    if (w == 0) {                     // wave 0 dumps its partial into LDS
        #pragma unroll
        for (int i = 0; i < 8; ++i) {
            float4 v0; v0.x=acc[i][0]; v0.y=acc[i][1]; v0.z=acc[i][2]; v0.w=acc[i][3];
            float4 v1; v1.x=acc[i][4]; v1.y=acc[i][5]; v1.z=acc[i][6]; v1.w=acc[i][7];
            *(float4*)&smem[(r0 + i) * 64 + c0]     = v0;
            *(float4*)&smem[(r0 + i) * 64 + c0 + 4] = v1;
        }
        if (l < 16) {
            #pragma unroll
            for (int k = 0; k < 4; ++k) {
                statd[0][4*l+k] = sqp[k];
                statd[1][4*l+k] = q2p[k];
                statd[2][4*l+k] = spp[k];
                statd[3][4*l+k] = p2p[k];
            }
        }
    }
    __syncthreads();

    if (w == 1) {                     // wave 1 merges and writes the record
        float* __restrict__ wsb = ws + (size_t)bid * WSB;
        #pragma unroll
        for (int i = 0; i < 8; ++i) {
            float4 d0 = *(const float4*)&smem[(r0 + i) * 64 + c0];
            float4 d1 = *(const float4*)&smem[(r0 + i) * 64 + c0 + 4];
            float4 v0; v0.x=acc[i][0]+d0.x; v0.y=acc[i][1]+d0.y; v0.z=acc[i][2]+d0.z; v0.w=acc[i][3]+d0.w;
            float4 v1; v1.x=acc[i][4]+d1.x; v1.y=acc[i][5]+d1.y; v1.z=acc[i][6]+d1.z; v1.w=acc[i][7]+d1.w;
            *(float4*)&wsb[(r0 + i) * 64 + c0]     = v0;
            *(float4*)&wsb[(r0 + i) * 64 + c0 + 4] = v1;
        }
        if (l < 16) {
            #pragma unroll
            for (int k = 0; k < 4; ++k) {
                wsb[4096 +   0 + 4*l+k] = statd[0][4*l+k] + sqp[k];
                wsb[4096 +  64 + 4*l+k] = statd[1][4*l+k] + q2p[k];
                wsb[4096 + 128 + 4*l+k] = statd[2][4*l+k] + spp[k];
                wsb[4096 + 192 + 4*l+k] = statd[3][4*l+k] + p2p[k];
            }
        }
    }
}

#define DOT16(KK, ARR) ({ \
    float4 x0 = *(const float4*)&ARR[sp4*16 +  0]; \
    float4 x1 = *(const float4*)&ARR[sp4*16 +  4]; \
    float4 x2 = *(const float4*)&ARR[sp4*16 +  8]; \
    float4 x3 = *(const float4*)&ARR[sp4*16 + 12]; \
    float a0 = 0.0f, a1 = 0.0f; \
    a0=fmaf(KK[0],x0.x,a0);  a1=fmaf(KK[1],x0.y,a1); \
    a0=fmaf(KK[2],x0.z,a0);  a1=fmaf(KK[3],x0.w,a1); \
    a0=fmaf(KK[4],x1.x,a0);  a1=fmaf(KK[5],x1.y,a1); \
    a0=fmaf(KK[6],x1.z,a0);  a1=fmaf(KK[7],x1.w,a1); \
    a0=fmaf(KK[8],x2.x,a0);  a1=fmaf(KK[9],x2.y,a1); \
    a0=fmaf(KK[10],x2.z,a0); a1=fmaf(KK[11],x2.w,a1); \
    a0=fmaf(KK[12],x3.x,a0); a1=fmaf(KK[13],x3.y,a1); \
    a0=fmaf(KK[14],x3.z,a0); a1=fmaf(KK[15],x3.w,a1); \
    a0 + a1; })

// ===================== Kernel B: combine + sim + K + Sinkhorn + logits =====================
__global__ __launch_bounds__(256)
void emd_solve(const float* __restrict__ ws, float* __restrict__ out)
{
    __shared__ __align__(16) float stage[16 * 64];          // colsum partials
    __shared__ __align__(16) float Kl [NN][68];
    __shared__ __align__(16) float KTl[NN][68];
    __shared__ __align__(16) float statL[4][NN];
    __shared__ __align__(16) float uL[NN];
    __shared__ __align__(16) float vL[NN];
    __shared__ __align__(16) float rL[NN];
    __shared__ __align__(16) float cL[NN];
    __shared__ float redl[4];

    const int b  = blockIdx.x;
    const int t  = threadIdx.x;
    const int tr = t >> 4, tc = t & 15;
    const int n0 = tr * 4, m0 = tc * 4;

    const float* __restrict__ wsb = ws + (size_t)b * SPLIT * WSB;

    float acc[4][4];
    #pragma unroll
    for (int i = 0; i < 4; ++i)
        #pragma unroll
        for (int j = 0; j < 4; ++j) acc[i][j] = 0.0f;
    #pragma unroll
    for (int s = 0; s < SPLIT; ++s) {
        const float* __restrict__ g = wsb + s * WSB;
        #pragma unroll
        for (int i = 0; i < 4; ++i) {
            float4 v = *(const float4*)&g[(n0 + i) * 64 + m0];
            acc[i][0] += v.x; acc[i][1] += v.y; acc[i][2] += v.z; acc[i][3] += v.w;
        }
    }
    if (t < NN) {
        float s0 = 0, s1 = 0, s2 = 0, s3 = 0;
        #pragma unroll
        for (int s = 0; s < SPLIT; ++s) {
            const float* __restrict__ g = wsb + s * WSB + 4096;
            s0 += g[t]; s1 += g[64 + t]; s2 += g[128 + t]; s3 += g[192 + t];
        }
        statL[0][t] = s0; statL[1][t] = s1; statL[2][t] = s2; statL[3][t] = s3;
    }
    #pragma unroll
    for (int i = 0; i < 4; ++i) {
        float s = acc[i][0] + acc[i][1] + acc[i][2] + acc[i][3];
        s += __shfl_xor(s, 1, 64); s += __shfl_xor(s, 2, 64);
        s += __shfl_xor(s, 4, 64); s += __shfl_xor(s, 8, 64);
        if (tc == 0) uL[n0 + i] = s;
    }
    #pragma unroll
    for (int j = 0; j < 4; ++j)
        stage[tr * 64 + m0 + j] = acc[0][j] + acc[1][j] + acc[2][j] + acc[3][j];
    __syncthreads();

    if (t < NN) {
        float cs = 0;
        #pragma unroll
        for (int i = 0; i < 16; ++i) cs += stage[i * 64 + t];
        float w2 = fmaxf(cs * (1.0f/64.0f), 0.0f) + 0.001f;
        float w1 = fmaxf(uL[t] * (1.0f/64.0f), 0.0f) + 0.001f;
        float s1 = w1, s2 = w2;
        #pragma unroll
        for (int m = 1; m < 64; m <<= 1) {
            s1 += __shfl_xor(s1, m, 64);
            s2 += __shfl_xor(s2, m, 64);
        }
        rL[t] = w1 / s1;
        cL[t] = w2 / s2;
        vL[t] = 1.0f;
    }
    {
        float nq_[4], np_[4], sqn[4], spm[4];
        #pragma unroll
        for (int i = 0; i < 4; ++i) {
            float sv  = statL[0][n0 + i];
            float var = statL[1][n0 + i] - sv * sv * (1.0f/1024.0f);
            nq_[i] = fmaxf(sqrtf(fmaxf(var, 0.0f)), 1e-8f);
            sqn[i] = sv;
        }
        #pragma unroll
        for (int j = 0; j < 4; ++j) {
            float sv  = statL[2][m0 + j];
            float var = statL[3][m0 + j] - sv * sv * (1.0f/1024.0f);
            np_[j] = fmaxf(sqrtf(fmaxf(var, 0.0f)), 1e-8f);
            spm[j] = sv;
        }
        #pragma unroll
        for (int i = 0; i < 4; ++i) {
            #pragma unroll
            for (int j = 0; j < 4; ++j) {
                float sim = (acc[i][j] - sqn[i] * spm[j] * (1.0f/1024.0f)) / (nq_[i] * np_[j]);
                acc[i][j] = sim;
                float Kv = exp2f((sim - 1.0f) * KSC);
                Kl [n0 + i][m0 + j] = Kv;
                KTl[m0 + j][n0 + i] = Kv;
            }
        }
    }
    __syncthreads();

    const int sn  = t >> 2;
    const int sp4 = t & 3;
    float Kr[16], KTr[16];
    #pragma unroll
    for (int jj = 0; jj < 4; ++jj) {
        float4 kv = *(const float4*)&Kl [sn][sp4 * 16 + jj * 4];
        float4 kt = *(const float4*)&KTl[sn][sp4 * 16 + jj * 4];
        Kr [jj*4+0]=kv.x; Kr [jj*4+1]=kv.y; Kr [jj*4+2]=kv.z; Kr [jj*4+3]=kv.w;
        KTr[jj*4+0]=kt.x; KTr[jj*4+1]=kt.y; KTr[jj*4+2]=kt.z; KTr[jj*4+3]=kt.w;
    }
    const float rreg = rL[sn];
    const float creg = cL[sn];

    for (int it = 0; it < 100; ++it) {
        float s = DOT16(Kr, vL);
        s += __shfl_xor(s, 1, 64); s += __shfl_xor(s, 2, 64);
        float u = rreg / fmaxf(s, 1e-30f);
        if (sp4 == 0) uL[sn] = u;
        __syncthreads();
        float s2 = DOT16(KTr, uL);
        s2 += __shfl_xor(s2, 1, 64); s2 += __shfl_xor(s2, 2, 64);
        float vv = creg / fmaxf(s2, 1e-30f);
        if (sp4 == 0) vL[sn] = vv;
        __syncthreads();
    }
    {
        float s = DOT16(Kr, vL);
        s += __shfl_xor(s, 1, 64); s += __shfl_xor(s, 2, 64);
        float u = rreg / fmaxf(s, 1e-30f);
        if (sp4 == 0) uL[sn] = u;
    }
    __syncthreads();

    float uu[4], vv_[4];
    #pragma unroll
    for (int i = 0; i < 4; ++i) uu[i]  = uL[n0 + i];
    #pragma unroll
    for (int j = 0; j < 4; ++j) vv_[j] = vL[m0 + j];
    float part = 0.0f;
    #pragma unroll
    for (int i = 0; i < 4; ++i) {
        #pragma unroll
        for (int j = 0; j < 4; ++j) {
            float sim = acc[i][j];
            float Kv  = exp2f((sim - 1.0f) * KSC);
            part = fmaf(sim * Kv, uu[i] * vv_[j], part);
        }
    }
    #pragma unroll
    for (int m = 1; m < 64; m <<= 1) part += __shfl_xor(part, m, 64);
    if ((t & 63) == 0) redl[t >> 6] = part;
    __syncthreads();
    if (t == 0) out[b] = (redl[0] + redl[1] + redl[2] + redl[3]) * (12.5f / 64.0f);
}

// ===================== Fallback: verified fused single-kernel path =====================
#define GRAM_CHUNK_BODY(NCHUNK_, QB_, PB_)                                     \
    for (int ch = 0; ch < (NCHUNK_); ++ch) {                                   \
        if (ch) __syncthreads();                                               \
        *(float4*)&stage[       ofs] = qv0;                                    \
        *(float4*)&stage[1024 + ofs] = qv1;                                    \
        *(float4*)&stage[2048 + ofs] = pv0;                                    \
        *(float4*)&stage[3072 + ofs] = pv1;                                    \
        float4 nq0, nq1, np0, np1;                                             \
        const bool more = (ch + 1 < (NCHUNK_));                                \
        if (more) {                                                            \
            const float* qn = (QB_) + (ch + 1) * 2048;                         \
            const float* pn = (PB_) + (ch + 1) * 2048;                         \
            nq0 = *(const float4*)(qn + ofs);                                  \
            nq1 = *(const float4*)(qn + 1024 + ofs);                           \
            np0 = *(const float4*)(pn + ofs);                                  \
            np1 = *(const float4*)(pn + 1024 + ofs);                           \
        }                                                                      \
        STAT_Q(qv0); STAT_Q(qv1);                                              \
        STAT_P(pv0); STAT_P(pv1);                                              \
        __syncthreads();                                                       \
        _Pragma("unroll 8")                                                    \
        for (int cc = 0; cc < CK; ++cc) {                                      \
            float4 a  = *(const float4*)&stage[cc * 64 + n0];                  \
            float4 bb = *(const float4*)&stage[2048 + cc * 64 + m0];           \
            acc[0][0]=fmaf(a.x,bb.x,acc[0][0]); acc[0][1]=fmaf(a.x,bb.y,acc[0][1]); \
            acc[0][2]=fmaf(a.x,bb.z,acc[0][2]); acc[0][3]=fmaf(a.x,bb.w,acc[0][3]); \
            acc[1][0]=fmaf(a.y,bb.x,acc[1][0]); acc[1][1]=fmaf(a.y,bb.y,acc[1][1]); \
            acc[1][2]=fmaf(a.y,bb.z,acc[1][2]); acc[1][3]=fmaf(a.y,bb.w,acc[1][3]); \
            acc[2][0]=fmaf(a.z,bb.x,acc[2][0]); acc[2][1]=fmaf(a.z,bb.y,acc[2][1]); \
            acc[2][2]=fmaf(a.z,bb.z,acc[2][2]); acc[2][3]=fmaf(a.z,bb.w,acc[2][3]); \
            acc[3][0]=fmaf(a.w,bb.x,acc[3][0]); acc[3][1]=fmaf(a.w,bb.y,acc[3][1]); \
            acc[3][2]=fmaf(a.w,bb.z,acc[3][2]); acc[3][3]=fmaf(a.w,bb.w,acc[3][3]); \
        }                                                                      \
        if (more) { qv0 = nq0; qv1 = nq1; pv0 = np0; pv1 = np1; }              \
    }

__global__ __launch_bounds__(256)
void deepemd_fused(const float* __restrict__ proto,
                   const float* __restrict__ query,
                   float* __restrict__ out)
{
    __shared__ __align__(16) float stage[2 * CK * NN];
    __shared__ __align__(16) float Kl [NN][68];
    __shared__ __align__(16) float KTl[NN][68];
    __shared__ __align__(16) float statL[4][NN];
    __shared__ __align__(16) float uL[NN];
    __shared__ __align__(16) float vL[NN];
    __shared__ __align__(16) float rL[NN];
    __shared__ __align__(16) float cL[NN];
    __shared__ float redl[4];

    const int b  = blockIdx.x;
    const int t  = threadIdx.x;
    const int tr = t >> 4, tc = t & 15;
    const int n0 = tr * 4, m0 = tc * 4;
    const int ofs = 4 * t;

    const float* __restrict__ pb = proto + (size_t)b * (NCH * NN);
    const float* __restrict__ qb = query + (size_t)b * (NCH * NN);

    float acc[4][4];
    #pragma unroll
    for (int i = 0; i < 4; ++i)
        #pragma unroll
        for (int j = 0; j < 4; ++j) acc[i][j] = 0.0f;
    float sqp[4] = {0,0,0,0}, q2p[4] = {0,0,0,0};
    float spp[4] = {0,0,0,0}, p2p[4] = {0,0,0,0};

    float4 qv0 = *(const float4*)(qb + ofs);
    float4 qv1 = *(const float4*)(qb + 1024 + ofs);
    float4 pv0 = *(const float4*)(pb + ofs);
    float4 pv1 = *(const float4*)(pb + 1024 + ofs);

    GRAM_CHUNK_BODY(NCH / CK, qb, pb)
    __syncthreads();

    #pragma unroll
    for (int i = 0; i < 4; ++i) {
        float s = acc[i][0] + acc[i][1] + acc[i][2] + acc[i][3];
        s += __shfl_xor(s, 1, 64); s += __shfl_xor(s, 2, 64);
        s += __shfl_xor(s, 4, 64); s += __shfl_xor(s, 8, 64);
        if (tc == 0) uL[n0 + i] = s;
    }
    #pragma unroll
    for (int k = 0; k < 4; ++k) {
        stage[t*16 +      k] = sqp[k];
        stage[t*16 +  4 + k] = q2p[k];
        stage[t*16 +  8 + k] = spp[k];
        stage[t*16 + 12 + k] = p2p[k];
    }
    __syncthreads();
    if (t < NN) {
        const int g = t >> 2, k = t & 3;
        float ssq = 0, sq2 = 0, ssp = 0, sp2 = 0;
        #pragma unroll
        for (int j = 0; j < 16; ++j) {
            const float* row = &stage[(j * 16 + g) * 16];
            ssq += row[k]; sq2 += row[4 + k]; ssp += row[8 + k]; sp2 += row[12 + k];
        }
        statL[0][t] = ssq; statL[1][t] = sq2; statL[2][t] = ssp; statL[3][t] = sp2;
    }
    __syncthreads();
    #pragma unroll
    for (int j = 0; j < 4; ++j)
        stage[tr * 64 + m0 + j] = acc[0][j] + acc[1][j] + acc[2][j] + acc[3][j];
    __syncthreads();
    if (t < NN) {
        float cs = 0;
        #pragma unroll
        for (int i = 0; i < 16; ++i) cs += stage[i * 64 + t];
        float w2 = fmaxf(cs * (1.0f/64.0f), 0.0f) + 0.001f;
        float w1 = fmaxf(uL[t] * (1.0f/64.0f), 0.0f) + 0.001f;
        float s1 = w1, s2 = w2;
        #pragma unroll
        for (int m = 1; m < 64; m <<= 1) {
            s1 += __shfl_xor(s1, m, 64);
            s2 += __shfl_xor(s2, m, 64);
        }
        rL[t] = w1 / s1;
        cL[t] = w2 / s2;
        vL[t] = 1.0f;
    }
    __syncthreads();

    {
        float nq_[4], np_[4], sqn[4], spm[4];
        #pragma unroll
        for (int i = 0; i < 4; ++i) {
            float sv  = statL[0][n0 + i];
            float var = statL[1][n0 + i] - sv * sv * (1.0f/1024.0f);
            nq_[i] = fmaxf(sqrtf(fmaxf(var, 0.0f)), 1e-8f);
            sqn[i] = sv;
        }
        #pragma unroll
        for (int j = 0; j < 4; ++j) {
            float sv  = statL[2][m0 + j];
            float var = statL[3][m0 + j] - sv * sv * (1.0f/1024.0f);
            np_[j] = fmaxf(sqrtf(fmaxf(var, 0.0f)), 1e-8f);
            spm[j] = sv;
        }
        #pragma unroll
        for (int i = 0; i < 4; ++i) {
            #pragma unroll
            for (int j = 0; j < 4; ++j) {
                float sim = (acc[i][j] - sqn[i] * spm[j] * (1.0f/1024.0f)) / (nq_[i] * np_[j]);
                acc[i][j] = sim;
                float Kv = exp2f((sim - 1.0f) * KSC);
                Kl [n0 + i][m0 + j] = Kv;
                KTl[m0 + j][n0 + i] = Kv;
            }
        }
    }
    __syncthreads();

    const int sn  = t >> 2;
    const int sp4 = t & 3;
    float Kr[16], KTr[16];
    #pragma unroll
    for (int jj = 0; jj < 4; ++jj) {
        float4 kv = *(const float4*)&Kl [sn][sp4 * 16 + jj * 4];
        float4 kt = *(const float4*)&KTl[sn][sp4 * 16 + jj * 4];
        Kr [jj*4+0]=kv.x; Kr [jj*4+1]=kv.y; Kr [jj*4+2]=kv.z; Kr [jj*4+3]=kv.w;
        KTr[jj*4+0]=kt.x; KTr[jj*4+1]=kt.y; KTr[jj*4+2]=kt.z; KTr[jj*4+3]=kt.w;
    }
    const float rreg = rL[sn];
    const float creg = cL[sn];

    for (int it = 0; it < 100; ++it) {
        float s = DOT16(Kr, vL);
        s += __shfl_xor(s, 1, 64); s += __shfl_xor(s, 2, 64);
        float u = rreg / fmaxf(s, 1e-30f);
        if (sp4 == 0) uL[sn] = u;
        __syncthreads();
        float s2 = DOT16(KTr, uL);
        s2 += __shfl_xor(s2, 1, 64); s2 += __shfl_xor(s2, 2, 64);
        float vv = creg / fmaxf(s2, 1e-30f);
        if (sp4 == 0) vL[sn] = vv;
        __syncthreads();
    }
    {
        float s = DOT16(Kr, vL);
        s += __shfl_xor(s, 1, 64); s += __shfl_xor(s, 2, 64);
        float u = rreg / fmaxf(s, 1e-30f);
        if (sp4 == 0) uL[sn] = u;
    }
    __syncthreads();

    float uu[4], vv_[4];
    #pragma unroll
    for (int i = 0; i < 4; ++i) uu[i]  = uL[n0 + i];
    #pragma unroll
    for (int j = 0; j < 4; ++j) vv_[j] = vL[m0 + j];
    float part = 0.0f;
    #pragma unroll
    for (int i = 0; i < 4; ++i) {
        #pragma unroll
        for (int j = 0; j < 4; ++j) {
            float sim = acc[i][j];
            float Kv  = exp2f((sim - 1.0f) * KSC);
            part = fmaf(sim * Kv, uu[i] * vv_[j], part);
        }
    }
    #pragma unroll
    for (int m = 1; m < 64; m <<= 1) part += __shfl_xor(part, m, 64);
    if ((t & 63) == 0) redl[t >> 6] = part;
    __syncthreads();
    if (t == 0) out[b] = (redl[0] + redl[1] + redl[2] + redl[3]) * (12.5f / 64.0f);
}

extern "C" void kernel_launch(void* const* d_in, const int* in_sizes, int n_in,
                              void* d_out, int out_size, void* d_ws, size_t ws_size,
                              hipStream_t stream) {
    const float* proto = (const float*)d_in[0];
    const float* query = (const float*)d_in[1];
    float* out = (float*)d_out;
    (void)in_sizes; (void)n_in; (void)out_size;

    const size_t need = (size_t)512 * SPLIT * WSB * sizeof(float);   // ~35.7 MB
    if (ws_size >= need) {
        gram_partial2<<<dim3(512 * SPLIT), dim3(128), 0, stream>>>(proto, query, (float*)d_ws);
        emd_solve    <<<dim3(512),         dim3(256), 0, stream>>>((const float*)d_ws, out);
    } else {
        deepemd_fused<<<dim3(512), dim3(256), 0, stream>>>(proto, query, out);
    }
}